// Round 6
// baseline (257.898 us; speedup 1.0000x reference)
//
#include <hip/hip_runtime.h>
#include <hip/hip_bf16.h>

#define NN 100000
#define NE 3200000
#define NF 512
#define NH 16
#define NC 40
#define NB 782          // ceil(NN/128) buckets of 128 nodes
#define CAP 5120        // max edges per bucket (mean 4096, std 64)
#define NBLK 128        // multisplit blocks
#define CHUNK 25000     // NE / NBLK
#define GEMMB 1563      // ceil(NN/64) gemm blocks

typedef __attribute__((ext_vector_type(4))) float f32x4;
typedef __attribute__((ext_vector_type(8))) short bf16x8;

static __device__ __forceinline__ unsigned short f2b(float f) {
    unsigned int u = __float_as_uint(f);
    u += 0x7FFFu + ((u >> 16) & 1u);   // round-to-nearest-even
    return (unsigned short)(u >> 16);
}
static __device__ __forceinline__ float b2f(unsigned short u) {
    return __uint_as_float(((unsigned int)u) << 16);
}

// ---------------- fused: GEMM1 (blocks 0..GEMMB-1) + edge histogram (rest) ----------------
// gemm: h1[n][j] = bf16( X[n] @ W1[:,j] )   (unscaled; dinv applied in agg1)
// hist: per-block bucket histogram of dst -> histG[b][NB]

__global__ void __launch_bounds__(256) kA_gemm_hist(const float* __restrict__ x,
                                                    const float* __restrict__ W1,
                                                    const int* __restrict__ ei,
                                                    unsigned short* __restrict__ h1,
                                                    int* __restrict__ histG) {
    __shared__ int smem[4096];   // 16KB: gemm -> packed W1 (8192 bf16), hist -> h[NB]
    if (blockIdx.x < GEMMB) {
        // ---- pack W1 into LDS (fragment layout) ----
        unsigned short* wl = (unsigned short*)smem;
        for (int idx = threadIdx.x; idx < 8192; idx += 256) {
            int s = idx >> 9;
            int l = (idx >> 3) & 63;
            int e = idx & 7;
            int k = s * 32 + (l >> 4) * 8 + e;
            wl[idx] = f2b(W1[k * 16 + (l & 15)]);
        }
        __syncthreads();
        int wave = threadIdx.x >> 6;
        int l = threadIdx.x & 63;
        int m0 = blockIdx.x * 64 + wave * 16;
        if (m0 >= NN) return;                    // after sync: safe
        int row = m0 + (l & 15);
        int krow = (l >> 4) * 8;
        const float* xr = x + (size_t)row * NF + krow;
        const unsigned short* wf = wl + l * 8;
        f32x4 acc = {0.f, 0.f, 0.f, 0.f};
#pragma unroll 4
        for (int s = 0; s < 16; ++s) {
            f32x4 xa = *(const f32x4*)(xr + s * 32);
            f32x4 xb = *(const f32x4*)(xr + s * 32 + 4);
            union { bf16x8 v; unsigned short u[8]; } a;
            a.u[0] = f2b(xa.x); a.u[1] = f2b(xa.y); a.u[2] = f2b(xa.z); a.u[3] = f2b(xa.w);
            a.u[4] = f2b(xb.x); a.u[5] = f2b(xb.y); a.u[6] = f2b(xb.z); a.u[7] = f2b(xb.w);
            bf16x8 b = *(const bf16x8*)(wf + s * 512);
            acc = __builtin_amdgcn_mfma_f32_16x16x32_bf16(a.v, b, acc, 0, 0, 0);
        }
        // C layout: col = l&15, row = (l>>4)*4 + r
#pragma unroll
        for (int r = 0; r < 4; ++r) {
            int orow = m0 + (l >> 4) * 4 + r;
            h1[(size_t)orow * NH + (l & 15)] = f2b(acc[r]);
        }
    } else {
        int* h = smem;
        for (int i = threadIdx.x; i < NB; i += 256) h[i] = 0;
        __syncthreads();
        int b = blockIdx.x - GEMMB;
        int e0 = b * CHUNK, e1 = min(NE, e0 + CHUNK);
        for (int e = e0 + threadIdx.x; e < e1; e += 256)
            atomicAdd(&h[((unsigned)ei[NE + e]) >> 7], 1);
        __syncthreads();
        for (int i = threadIdx.x; i < NB; i += 256)
            histG[b * NB + i] = h[i];    // coalesced row write
    }
}

// ---------------- per-bucket scan over the 128 scatter blocks ----------------
// 391 blocks x 256 threads; each 128-thread half scans one bucket column

__global__ void __launch_bounds__(256) k_colscan(const int* __restrict__ histG,
                                                 int* __restrict__ ofsG,
                                                 int* __restrict__ bcnt) {
    __shared__ int sh[256];
    int t = threadIdx.x;
    int k = blockIdx.x * 2 + (t >> 7);   // bucket (< 782 always: 391*2 = 782)
    int tt = t & 127;                    // scatter-block index
    int v = histG[tt * NB + k];
    sh[t] = v;
    __syncthreads();
    for (int off = 1; off < 128; off <<= 1) {
        int add = (tt >= off) ? sh[t - off] : 0;
        __syncthreads();
        sh[t] += add;
        __syncthreads();
    }
    ofsG[k * NBLK + tt] = sh[t] - v;     // exclusive, coalesced
    if (tt == 127) bcnt[k] = sh[t];
}

// ---------------- scan bucket totals ----------------

__global__ void k_bscan(const int* __restrict__ bcnt, int* __restrict__ bptr,
                        int* __restrict__ rowptr) {
    __shared__ int sh[1024];
    int t = threadIdx.x;
    int v = (t < NB) ? bcnt[t] : 0;
    sh[t] = v;
    __syncthreads();
    for (int off = 1; off < 1024; off <<= 1) {
        int add = (t >= off) ? sh[t - off] : 0;
        __syncthreads();
        sh[t] += add;
        __syncthreads();
    }
    if (t < NB) bptr[t] = sh[t] - v;
    if (t == 0) { bptr[NB] = NE; rowptr[NN] = NE; }
}

// ---------------- scatter via LDS cursors (no global atomics) ----------------

__global__ void __launch_bounds__(1024) k_msscatter(const int* __restrict__ ei,
                                                    const int* __restrict__ bptr,
                                                    const int* __restrict__ ofsG,
                                                    unsigned int* __restrict__ pairs) {
    __shared__ int lcur[NB];
    int b = blockIdx.x;
    for (int k = threadIdx.x; k < NB; k += 1024)
        lcur[k] = bptr[k] + ofsG[k * NBLK + b];
    __syncthreads();
    int e0 = b * CHUNK, e1 = min(NE, e0 + CHUNK);
    for (int e = e0 + threadIdx.x; e < e1; e += 1024) {
        unsigned int s = (unsigned int)ei[e];
        unsigned int d = (unsigned int)ei[NE + e];
        int pos = atomicAdd(&lcur[d >> 7], 1);
        pairs[pos] = s | ((d & 127u) << 17);
    }
}

// ---------------- per-bucket counting sort -> CSR (rowptr, dinv, ssrc) ----------------

__global__ void __launch_bounds__(256) k_bsort(const unsigned int* __restrict__ pairs,
                                               const int* __restrict__ bptr,
                                               int* __restrict__ rowptr,
                                               float* __restrict__ dinv,
                                               int* __restrict__ ssrc) {
    __shared__ unsigned int ein[CAP];
    __shared__ unsigned int srt[CAP];
    __shared__ int lcnt[128], lofs[128], lcur[128];
    int b = blockIdx.x;
    int s0 = bptr[b], s1 = bptr[b + 1];
    int n = s1 - s0;
    for (int i = threadIdx.x; i < n; i += 256) ein[i] = pairs[s0 + i];
    if (threadIdx.x < 128) lcnt[threadIdx.x] = 0;
    __syncthreads();
    for (int i = threadIdx.x; i < n; i += 256) atomicAdd(&lcnt[ein[i] >> 17], 1);
    __syncthreads();
    if (threadIdx.x < 128) lofs[threadIdx.x] = lcnt[threadIdx.x];
    __syncthreads();
    for (int off = 1; off < 128; off <<= 1) {
        int add = 0;
        if (threadIdx.x < 128 && threadIdx.x >= off) add = lofs[threadIdx.x - off];
        __syncthreads();
        if (threadIdx.x < 128) lofs[threadIdx.x] += add;
        __syncthreads();
    }
    if (threadIdx.x < 128) {
        int excl = lofs[threadIdx.x] - lcnt[threadIdx.x];
        lcur[threadIdx.x] = excl;
        int node = b * 128 + threadIdx.x;
        if (node < NN) {
            rowptr[node] = s0 + excl;
            dinv[node] = rsqrtf((float)(lcnt[threadIdx.x] + 1));
        }
    }
    __syncthreads();
    for (int i = threadIdx.x; i < n; i += 256) {
        unsigned int v = ein[i];
        int pos = atomicAdd(&lcur[v >> 17], 1);
        srt[pos] = v & 0x1FFFFu;
    }
    __syncthreads();
    for (int i = threadIdx.x; i < n; i += 256) ssrc[s0 + i] = (int)srt[i];
}

// ---------------- layer-1 aggregation: one wave per node ----------------
// h1 unscaled: acc = h1[node]*di + sum h1[src]*dinv[src];  r1 = bf16(relu(acc*di+b1)*di)

__global__ void __launch_bounds__(256) k_agg1(const unsigned short* __restrict__ hs,
                                              const int* __restrict__ rowptr,
                                              const int* __restrict__ ssrc,
                                              const float* __restrict__ dinv,
                                              const float* __restrict__ b1,
                                              unsigned short* __restrict__ r1) {
    int l = threadIdx.x & 63;
    int node = blockIdx.x * 4 + (threadIdx.x >> 6);
    int j = l & 15;
    int ec = l >> 4;
    float di = dinv[node];
    int s = rowptr[node];
    int e1 = rowptr[node + 1];
    float acc = (ec == 0) ? b2f(hs[(size_t)node * NH + j]) * di : 0.0f;
#pragma unroll 4
    for (int e = s + ec; e < e1; e += 4) {
        int src = ssrc[e];
        acc += b2f(hs[(size_t)src * NH + j]) * dinv[src];
    }
    acc += __shfl_xor(acc, 16, 64);
    acc += __shfl_xor(acc, 32, 64);
    if (ec == 0) {
        float o = fmaxf(acc * di + b1[j], 0.0f) * di;
        r1[(size_t)node * NH + j] = f2b(o);
    }
}

// ---------------- layer-2 aggregation + classifier + log_softmax ----------------
// rs pre-scaled by dinv[src] already

__global__ void __launch_bounds__(256) k_agg2(const unsigned short* __restrict__ rs,
                                              const int* __restrict__ rowptr,
                                              const int* __restrict__ ssrc,
                                              const float* __restrict__ dinv,
                                              const float* __restrict__ W2,
                                              const float* __restrict__ b2,
                                              float* __restrict__ out) {
    __shared__ float w[NH * NC];
    __shared__ float bb[NC];
    int t = threadIdx.x;
    for (int i = t; i < NH * NC; i += 256) w[i] = W2[i];
    if (t < NC) bb[t] = b2[t];
    __syncthreads();
    int l = t & 63;
    int node = blockIdx.x * 4 + (t >> 6);
    int j = l & 15;
    int ec = l >> 4;
    float di = dinv[node];
    int s = rowptr[node];
    int e1 = rowptr[node + 1];
    float acc = (ec == 0) ? b2f(rs[(size_t)node * NH + j]) : 0.0f;
#pragma unroll 4
    for (int e = s + ec; e < e1; e += 4) {
        int src = ssrc[e];
        acc += b2f(rs[(size_t)src * NH + j]);
    }
    acc += __shfl_xor(acc, 16, 64);
    acc += __shfl_xor(acc, 32, 64);
    // lanes 0-15 hold z[j] = acc*di; broadcast to 40 class lanes
    float zv = acc * di;
    float lg = (l < NC) ? bb[l] : -1e30f;
#pragma unroll
    for (int k = 0; k < NH; ++k) {
        float zk = __shfl(zv, k, 64);
        if (l < NC) lg += zk * w[k * NC + l];
    }
    float mx = lg;
#pragma unroll
    for (int off = 1; off < 64; off <<= 1) mx = fmaxf(mx, __shfl_xor(mx, off, 64));
    float ex = (l < NC) ? __expf(lg - mx) : 0.0f;
    float sm = ex;
#pragma unroll
    for (int off = 1; off < 64; off <<= 1) sm += __shfl_xor(sm, off, 64);
    if (l < NC) out[(size_t)node * NC + l] = lg - mx - __logf(sm);
}

// ---------------- launch ----------------

extern "C" void kernel_launch(void* const* d_in, const int* in_sizes, int n_in,
                              void* d_out, int out_size, void* d_ws, size_t ws_size,
                              hipStream_t stream) {
    const float* x  = (const float*)d_in[0];
    const int*   ei = (const int*)d_in[1];
    const float* W1 = (const float*)d_in[2];
    const float* b1 = (const float*)d_in[3];
    const float* W2 = (const float*)d_in[4];
    const float* b2 = (const float*)d_in[5];
    float* out = (float*)d_out;

    char* ws = (char*)d_ws;
    size_t off = 0;
    auto alloc = [&](size_t bytes) -> void* {
        void* p = ws + off;
        off += (bytes + 255) & ~(size_t)255;
        return p;
    };
    int* histG      = (int*)alloc((size_t)NBLK * NB * 4);
    int* ofsG       = (int*)alloc((size_t)NB * NBLK * 4);
    int* bcnt       = (int*)alloc((size_t)NB * 4);
    int* bptr       = (int*)alloc((size_t)(NB + 1) * 4);
    int* rowptr     = (int*)alloc((size_t)(NN + 1) * 4);
    float* dinv     = (float*)alloc((size_t)NN * 4);
    unsigned int* pairs = (unsigned int*)alloc((size_t)NE * 4);
    int* ssrc       = (int*)alloc((size_t)NE * 4);
    unsigned short* h1  = (unsigned short*)alloc((size_t)NN * NH * 2);  // bf16, unscaled
    unsigned short* r1  = (unsigned short*)alloc((size_t)NN * NH * 2);  // bf16, pre-scaled

    kA_gemm_hist<<<GEMMB + NBLK, 256, 0, stream>>>(x, W1, ei, h1, histG);
    k_colscan<<<NB / 2, 256, 0, stream>>>(histG, ofsG, bcnt);
    k_bscan<<<1, 1024, 0, stream>>>(bcnt, bptr, rowptr);
    k_msscatter<<<NBLK, 1024, 0, stream>>>(ei, bptr, ofsG, pairs);
    k_bsort<<<NB, 256, 0, stream>>>(pairs, bptr, rowptr, dinv, ssrc);
    k_agg1<<<NN / 4, 256, 0, stream>>>(h1, rowptr, ssrc, dinv, b1, r1);
    k_agg2<<<NN / 4, 256, 0, stream>>>(r1, rowptr, ssrc, dinv, W2, b2, out);
}

// Round 7
// 255.342 us; speedup vs baseline: 1.0100x; 1.0100x over previous
//
#include <hip/hip_runtime.h>
#include <hip/hip_bf16.h>

#define NN 100000
#define NE 3200000
#define NF 512
#define NH 16
#define NC 40
#define BKT_SH 6
#define NBKT 1563       // ceil(NN/64) buckets of 64 nodes
#define CAP2 2560       // max edges/bucket (mean 2047, sigma 45, +11 sigma)
#define NBLK 512        // multisplit blocks
#define CHUNK 6250      // NE / NBLK
#define GEMMB 1563      // ceil(NN/64) gemm blocks

typedef __attribute__((ext_vector_type(4))) float f32x4;
typedef __attribute__((ext_vector_type(8))) short bf16x8;

static __device__ __forceinline__ unsigned short f2b(float f) {
    unsigned int u = __float_as_uint(f);
    u += 0x7FFFu + ((u >> 16) & 1u);   // round-to-nearest-even
    return (unsigned short)(u >> 16);
}
static __device__ __forceinline__ float b2f(unsigned short u) {
    return __uint_as_float(((unsigned int)u) << 16);
}

// ---------------- fused: every block does a GEMM tile; blocks<NBLK also hist first ----------
// gemm: h1[n][j] = bf16( X[n] @ W1[:,j] )   (unscaled; dinv applied in agg1)

__global__ void __launch_bounds__(256) kA_gemm_hist(const float* __restrict__ x,
                                                    const float* __restrict__ W1,
                                                    const int* __restrict__ ei,
                                                    unsigned short* __restrict__ h1,
                                                    int* __restrict__ histG) {
    __shared__ int smem[4096];   // 16KB: hist h[NBKT] then packed W1 (8192 bf16)
    int tid = threadIdx.x;
    if (blockIdx.x < NBLK) {     // hist slice first (hidden under gemm occupancy)
        int* h = smem;
        for (int i = tid; i < NBKT; i += 256) h[i] = 0;
        __syncthreads();
        int b = blockIdx.x;
        int e0 = b * CHUNK, e1 = min(NE, e0 + CHUNK);
        for (int e = e0 + tid; e < e1; e += 256)
            atomicAdd(&h[((unsigned)ei[NE + e]) >> BKT_SH], 1);
        __syncthreads();
        for (int i = tid; i < NBKT; i += 256)
            histG[b * NBKT + i] = h[i];       // coalesced row write
        __syncthreads();
    }
    // ---- pack W1 into LDS (fragment layout) ----
    unsigned short* wl = (unsigned short*)smem;
    for (int idx = tid; idx < 8192; idx += 256) {
        int s = idx >> 9;
        int l = (idx >> 3) & 63;
        int e = idx & 7;
        int k = s * 32 + (l >> 4) * 8 + e;
        wl[idx] = f2b(W1[k * 16 + (l & 15)]);
    }
    __syncthreads();
    int wave = tid >> 6;
    int l = tid & 63;
    int m0 = blockIdx.x * 64 + wave * 16;
    if (m0 >= NN) return;
    int row = m0 + (l & 15);
    int krow = (l >> 4) * 8;
    const float* xr = x + (size_t)row * NF + krow;
    const unsigned short* wf = wl + l * 8;
    f32x4 acc = {0.f, 0.f, 0.f, 0.f};
#pragma unroll 4
    for (int s = 0; s < 16; ++s) {
        f32x4 xa = *(const f32x4*)(xr + s * 32);
        f32x4 xb = *(const f32x4*)(xr + s * 32 + 4);
        union { bf16x8 v; unsigned short u[8]; } a;
        a.u[0] = f2b(xa.x); a.u[1] = f2b(xa.y); a.u[2] = f2b(xa.z); a.u[3] = f2b(xa.w);
        a.u[4] = f2b(xb.x); a.u[5] = f2b(xb.y); a.u[6] = f2b(xb.z); a.u[7] = f2b(xb.w);
        bf16x8 b = *(const bf16x8*)(wf + s * 512);
        acc = __builtin_amdgcn_mfma_f32_16x16x32_bf16(a.v, b, acc, 0, 0, 0);
    }
    // C layout: col = l&15, row = (l>>4)*4 + r
#pragma unroll
    for (int r = 0; r < 4; ++r) {
        int orow = m0 + (l >> 4) * 4 + r;
        h1[(size_t)orow * NH + (l & 15)] = f2b(acc[r]);
    }
}

// ---------------- per-bucket scan over the 512 scatter blocks ----------------

__global__ void __launch_bounds__(512) k_colscan(const int* __restrict__ histG,
                                                 int* __restrict__ ofsG,
                                                 int* __restrict__ bcnt) {
    __shared__ int sh[NBLK];
    int k = blockIdx.x;          // bucket
    int t = threadIdx.x;         // scatter-block index
    int v = histG[t * NBKT + k];
    sh[t] = v;
    __syncthreads();
    for (int off = 1; off < NBLK; off <<= 1) {
        int add = (t >= off) ? sh[t - off] : 0;
        __syncthreads();
        sh[t] += add;
        __syncthreads();
    }
    ofsG[k * NBLK + t] = sh[t] - v;   // exclusive, coalesced
    if (t == NBLK - 1) bcnt[k] = sh[t];
}

// ---------------- scan bucket totals (1563 elements, 2/thread) ----------------

__global__ void k_bscan(const int* __restrict__ bcnt, int* __restrict__ bptr,
                        int* __restrict__ rowptr) {
    __shared__ int sh[1024];
    int t = threadIdx.x;
    int i0 = 2 * t, i1 = 2 * t + 1;
    int a = (i0 < NBKT) ? bcnt[i0] : 0;
    int b = (i1 < NBKT) ? bcnt[i1] : 0;
    int pair = a + b;
    sh[t] = pair;
    __syncthreads();
    for (int off = 1; off < 1024; off <<= 1) {
        int add = (t >= off) ? sh[t - off] : 0;
        __syncthreads();
        sh[t] += add;
        __syncthreads();
    }
    int excl = sh[t] - pair;
    if (i0 < NBKT) bptr[i0] = excl;
    if (i1 < NBKT) bptr[i1] = excl + a;
    if (t == 0) { bptr[NBKT] = NE; rowptr[NN] = NE; }
}

// ---------------- scatter via LDS cursors (no global atomics) ----------------

__global__ void __launch_bounds__(512) k_msscatter(const int* __restrict__ ei,
                                                   const int* __restrict__ bptr,
                                                   const int* __restrict__ ofsG,
                                                   unsigned int* __restrict__ pairs) {
    __shared__ int lcur[NBKT];
    int b = blockIdx.x;
    for (int k = threadIdx.x; k < NBKT; k += 512)
        lcur[k] = bptr[k] + ofsG[k * NBLK + b];
    __syncthreads();
    int e0 = b * CHUNK, e1 = min(NE, e0 + CHUNK);
    for (int e = e0 + threadIdx.x; e < e1; e += 512) {
        unsigned int s = (unsigned int)ei[e];
        unsigned int d = (unsigned int)ei[NE + e];
        int pos = atomicAdd(&lcur[d >> BKT_SH], 1);
        pairs[pos] = s | ((d & 63u) << 17);
    }
}

// ---------------- per-bucket (64 nodes) counting sort -> CSR ----------------

__global__ void __launch_bounds__(256) k_bsort(const unsigned int* __restrict__ pairs,
                                               const int* __restrict__ bptr,
                                               int* __restrict__ rowptr,
                                               float* __restrict__ dinv,
                                               int* __restrict__ ssrc) {
    __shared__ unsigned int ein[CAP2];
    __shared__ unsigned int srt[CAP2];
    __shared__ int lcnt[64], lofs[64], lcur[64];
    int b = blockIdx.x;
    int s0 = bptr[b], s1 = bptr[b + 1];
    int n = s1 - s0;
    for (int i = threadIdx.x; i < n; i += 256) ein[i] = pairs[s0 + i];
    if (threadIdx.x < 64) lcnt[threadIdx.x] = 0;
    __syncthreads();
    for (int i = threadIdx.x; i < n; i += 256) atomicAdd(&lcnt[ein[i] >> 17], 1);
    __syncthreads();
    if (threadIdx.x < 64) lofs[threadIdx.x] = lcnt[threadIdx.x];
    __syncthreads();
    for (int off = 1; off < 64; off <<= 1) {
        int add = 0;
        if (threadIdx.x < 64 && threadIdx.x >= off) add = lofs[threadIdx.x - off];
        __syncthreads();
        if (threadIdx.x < 64) lofs[threadIdx.x] += add;
        __syncthreads();
    }
    if (threadIdx.x < 64) {
        int excl = lofs[threadIdx.x] - lcnt[threadIdx.x];
        lcur[threadIdx.x] = excl;
        int node = b * 64 + threadIdx.x;
        if (node < NN) {
            rowptr[node] = s0 + excl;
            dinv[node] = rsqrtf((float)(lcnt[threadIdx.x] + 1));
        }
    }
    __syncthreads();
    for (int i = threadIdx.x; i < n; i += 256) {
        unsigned int v = ein[i];
        int pos = atomicAdd(&lcur[v >> 17], 1);
        srt[pos] = v & 0x1FFFFu;
    }
    __syncthreads();
    for (int i = threadIdx.x; i < n; i += 256) ssrc[s0 + i] = (int)srt[i];
}

// ---------------- layer-1 aggregation: one wave per node ----------------
// h1 unscaled: acc = h1[node]*di + sum h1[src]*dinv[src];  r1 = bf16(relu(acc*di+b1)*di)

__global__ void __launch_bounds__(256) k_agg1(const unsigned short* __restrict__ hs,
                                              const int* __restrict__ rowptr,
                                              const int* __restrict__ ssrc,
                                              const float* __restrict__ dinv,
                                              const float* __restrict__ b1,
                                              unsigned short* __restrict__ r1) {
    int l = threadIdx.x & 63;
    int node = blockIdx.x * 4 + (threadIdx.x >> 6);
    int j = l & 15;
    int ec = l >> 4;
    float di = dinv[node];
    int s = rowptr[node];
    int e1 = rowptr[node + 1];
    float acc = (ec == 0) ? b2f(hs[(size_t)node * NH + j]) * di : 0.0f;
#pragma unroll 4
    for (int e = s + ec; e < e1; e += 4) {
        int src = ssrc[e];
        acc += b2f(hs[(size_t)src * NH + j]) * dinv[src];
    }
    acc += __shfl_xor(acc, 16, 64);
    acc += __shfl_xor(acc, 32, 64);
    if (ec == 0) {
        float o = fmaxf(acc * di + b1[j], 0.0f) * di;
        r1[(size_t)node * NH + j] = f2b(o);
    }
}

// ---------------- layer-2 aggregation + classifier + log_softmax ----------------
// rs pre-scaled by dinv[src] already

__global__ void __launch_bounds__(256) k_agg2(const unsigned short* __restrict__ rs,
                                              const int* __restrict__ rowptr,
                                              const int* __restrict__ ssrc,
                                              const float* __restrict__ dinv,
                                              const float* __restrict__ W2,
                                              const float* __restrict__ b2,
                                              float* __restrict__ out) {
    __shared__ float w[NH * NC];
    __shared__ float bb[NC];
    int t = threadIdx.x;
    for (int i = t; i < NH * NC; i += 256) w[i] = W2[i];
    if (t < NC) bb[t] = b2[t];
    __syncthreads();
    int l = t & 63;
    int node = blockIdx.x * 4 + (t >> 6);
    int j = l & 15;
    int ec = l >> 4;
    float di = dinv[node];
    int s = rowptr[node];
    int e1 = rowptr[node + 1];
    float acc = (ec == 0) ? b2f(rs[(size_t)node * NH + j]) : 0.0f;
#pragma unroll 4
    for (int e = s + ec; e < e1; e += 4) {
        int src = ssrc[e];
        acc += b2f(rs[(size_t)src * NH + j]);
    }
    acc += __shfl_xor(acc, 16, 64);
    acc += __shfl_xor(acc, 32, 64);
    // lanes 0-15 hold z[j] = acc*di; broadcast to 40 class lanes
    float zv = acc * di;
    float lg = (l < NC) ? bb[l] : -1e30f;
#pragma unroll
    for (int k = 0; k < NH; ++k) {
        float zk = __shfl(zv, k, 64);
        if (l < NC) lg += zk * w[k * NC + l];
    }
    float mx = lg;
#pragma unroll
    for (int off = 1; off < 64; off <<= 1) mx = fmaxf(mx, __shfl_xor(mx, off, 64));
    float ex = (l < NC) ? __expf(lg - mx) : 0.0f;
    float sm = ex;
#pragma unroll
    for (int off = 1; off < 64; off <<= 1) sm += __shfl_xor(sm, off, 64);
    if (l < NC) out[(size_t)node * NC + l] = lg - mx - __logf(sm);
}

// ---------------- launch ----------------

extern "C" void kernel_launch(void* const* d_in, const int* in_sizes, int n_in,
                              void* d_out, int out_size, void* d_ws, size_t ws_size,
                              hipStream_t stream) {
    const float* x  = (const float*)d_in[0];
    const int*   ei = (const int*)d_in[1];
    const float* W1 = (const float*)d_in[2];
    const float* b1 = (const float*)d_in[3];
    const float* W2 = (const float*)d_in[4];
    const float* b2 = (const float*)d_in[5];
    float* out = (float*)d_out;

    char* ws = (char*)d_ws;
    size_t off = 0;
    auto alloc = [&](size_t bytes) -> void* {
        void* p = ws + off;
        off += (bytes + 255) & ~(size_t)255;
        return p;
    };
    int* histG      = (int*)alloc((size_t)NBLK * NBKT * 4);
    int* ofsG       = (int*)alloc((size_t)NBKT * NBLK * 4);
    int* bcnt       = (int*)alloc((size_t)NBKT * 4);
    int* bptr       = (int*)alloc((size_t)(NBKT + 1) * 4);
    int* rowptr     = (int*)alloc((size_t)(NN + 1) * 4);
    float* dinv     = (float*)alloc((size_t)NN * 4);
    unsigned int* pairs = (unsigned int*)alloc((size_t)NE * 4);
    int* ssrc       = (int*)alloc((size_t)NE * 4);
    unsigned short* h1  = (unsigned short*)alloc((size_t)NN * NH * 2);  // bf16, unscaled
    unsigned short* r1  = (unsigned short*)alloc((size_t)NN * NH * 2);  // bf16, pre-scaled

    kA_gemm_hist<<<GEMMB, 256, 0, stream>>>(x, W1, ei, h1, histG);
    k_colscan<<<NBKT, NBLK, 0, stream>>>(histG, ofsG, bcnt);
    k_bscan<<<1, 1024, 0, stream>>>(bcnt, bptr, rowptr);
    k_msscatter<<<NBLK, 512, 0, stream>>>(ei, bptr, ofsG, pairs);
    k_bsort<<<NBKT, 256, 0, stream>>>(pairs, bptr, rowptr, dinv, ssrc);
    k_agg1<<<NN / 4, 256, 0, stream>>>(h1, rowptr, ssrc, dinv, b1, r1);
    k_agg2<<<NN / 4, 256, 0, stream>>>(r1, rowptr, ssrc, dinv, W2, b2, out);
}

// Round 8
// 222.454 us; speedup vs baseline: 1.1593x; 1.1478x over previous
//
#include <hip/hip_runtime.h>
#include <hip/hip_bf16.h>

#define NN 100000
#define NE 3200000
#define NF 512
#define NH 16
#define NC 40
#define BKT_SH 8
#define NBKT 391        // buckets of 256 nodes (391*256 = 100096)
#define CAP 8960        // max edges/bucket (mean 8192, sigma ~91, +8.5 sigma)
#define HISTB 1536      // hist rows (blocks doing hist inside kA)
#define CHUNK_H 2084    // edges per hist row (1536*2084 = 3201024 >= NE)
#define SCATB 256       // scatter blocks
#define ROWS_PER_SCAT 6 // hist rows per scatter block (1536/256)
#define CHUNK_S 12504   // edges per scatter block (6*2084)
#define GEMMB 1563      // ceil(NN/64)

typedef __attribute__((ext_vector_type(4))) float f32x4;
typedef __attribute__((ext_vector_type(8))) short bf16x8;

static __device__ __forceinline__ unsigned short f2b(float f) {
    unsigned int u = __float_as_uint(f);
    u += 0x7FFFu + ((u >> 16) & 1u);   // round-to-nearest-even
    return (unsigned short)(u >> 16);
}
static __device__ __forceinline__ float b2f(unsigned short u) {
    return __uint_as_float(((unsigned int)u) << 16);
}

// ---------------- fused: every block a GEMM tile; blocks<HISTB do a small hist slice first --

__global__ void __launch_bounds__(256) kA_gemm_hist(const float* __restrict__ x,
                                                    const float* __restrict__ W1,
                                                    const int* __restrict__ ei,
                                                    unsigned short* __restrict__ h1,
                                                    int* __restrict__ histG) {
    __shared__ int smem[4096];   // 16KB: hist h[NBKT] first, then packed W1 (8192 bf16)
    int tid = threadIdx.x;
    if (blockIdx.x < HISTB) {    // ~8 iterations: amortized under gemm
        int* h = smem;
        for (int i = tid; i < NBKT; i += 256) h[i] = 0;
        __syncthreads();
        int r = blockIdx.x;
        int e0 = r * CHUNK_H, e1 = min(NE, e0 + CHUNK_H);
        for (int e = e0 + tid; e < e1; e += 256)
            atomicAdd(&h[((unsigned)ei[NE + e]) >> BKT_SH], 1);
        __syncthreads();
        for (int i = tid; i < NBKT; i += 256)
            histG[r * NBKT + i] = h[i];
        __syncthreads();
    }
    // ---- pack W1 into LDS (fragment layout) ----
    unsigned short* wl = (unsigned short*)smem;
    for (int idx = tid; idx < 8192; idx += 256) {
        int s = idx >> 9;
        int l = (idx >> 3) & 63;
        int e = idx & 7;
        int k = s * 32 + (l >> 4) * 8 + e;
        wl[idx] = f2b(W1[k * 16 + (l & 15)]);
    }
    __syncthreads();
    int wave = tid >> 6;
    int l = tid & 63;
    int m0 = blockIdx.x * 64 + wave * 16;
    if (m0 >= NN) return;
    int row = m0 + (l & 15);
    int krow = (l >> 4) * 8;
    const float* xr = x + (size_t)row * NF + krow;
    const unsigned short* wf = wl + l * 8;
    f32x4 acc = {0.f, 0.f, 0.f, 0.f};
#pragma unroll 4
    for (int s = 0; s < 16; ++s) {
        f32x4 xa = *(const f32x4*)(xr + s * 32);
        f32x4 xb = *(const f32x4*)(xr + s * 32 + 4);
        union { bf16x8 v; unsigned short u[8]; } a;
        a.u[0] = f2b(xa.x); a.u[1] = f2b(xa.y); a.u[2] = f2b(xa.z); a.u[3] = f2b(xa.w);
        a.u[4] = f2b(xb.x); a.u[5] = f2b(xb.y); a.u[6] = f2b(xb.z); a.u[7] = f2b(xb.w);
        bf16x8 b = *(const bf16x8*)(wf + s * 512);
        acc = __builtin_amdgcn_mfma_f32_16x16x32_bf16(a.v, b, acc, 0, 0, 0);
    }
    // C layout: col = l&15, row = (l>>4)*4 + r
#pragma unroll
    for (int r = 0; r < 4; ++r) {
        int orow = m0 + (l >> 4) * 4 + r;
        h1[(size_t)orow * NH + (l & 15)] = f2b(acc[r]);
    }
}

// ---------------- per-bucket scan over the 1536 hist rows (3 rows/thread) ----------------
// emits ofsG[k][b] = prefix at row 6b, and bcnt[k] = column total

__global__ void __launch_bounds__(512) k_colscan(const int* __restrict__ histG,
                                                 int* __restrict__ ofsG,
                                                 int* __restrict__ bcnt) {
    __shared__ int sh[512];
    int k = blockIdx.x;
    int t = threadIdx.x;
    int base = t * 3;
    int a0 = histG[(size_t)(base + 0) * NBKT + k];
    int a1 = histG[(size_t)(base + 1) * NBKT + k];
    int a2 = histG[(size_t)(base + 2) * NBKT + k];
    int s = a0 + a1 + a2;
    sh[t] = s;
    __syncthreads();
    for (int off = 1; off < 512; off <<= 1) {
        int add = (t >= off) ? sh[t - off] : 0;
        __syncthreads();
        sh[t] += add;
        __syncthreads();
    }
    int excl = sh[t] - s;
    if ((t & 1) == 0) ofsG[(size_t)k * SCATB + (t >> 1)] = excl;  // row 6b = thread 2b start
    if (t == 511) bcnt[k] = sh[t];
}

// ---------------- scan bucket totals (391) ----------------

__global__ void k_bscan(const int* __restrict__ bcnt, int* __restrict__ bptr,
                        int* __restrict__ rowptr) {
    __shared__ int sh[512];
    int t = threadIdx.x;
    int v = (t < NBKT) ? bcnt[t] : 0;
    sh[t] = v;
    __syncthreads();
    for (int off = 1; off < 512; off <<= 1) {
        int add = (t >= off) ? sh[t - off] : 0;
        __syncthreads();
        sh[t] += add;
        __syncthreads();
    }
    if (t < NBKT) bptr[t] = sh[t] - v;
    if (t == 0) { bptr[NBKT] = NE; rowptr[NN] = NE; }
}

// ---------------- scatter via LDS cursors; 128B avg segments per (block,bucket) ------------

__global__ void __launch_bounds__(1024) k_msscatter(const int* __restrict__ ei,
                                                    const int* __restrict__ bptr,
                                                    const int* __restrict__ ofsG,
                                                    unsigned int* __restrict__ pairs) {
    __shared__ int lcur[NBKT];
    int b = blockIdx.x;
    for (int k = threadIdx.x; k < NBKT; k += 1024)
        lcur[k] = bptr[k] + ofsG[(size_t)k * SCATB + b];
    __syncthreads();
    int e0 = b * CHUNK_S, e1 = min(NE, e0 + CHUNK_S);
    for (int e = e0 + threadIdx.x; e < e1; e += 1024) {
        unsigned int s = (unsigned int)ei[e];
        unsigned int d = (unsigned int)ei[NE + e];
        int pos = atomicAdd(&lcur[d >> BKT_SH], 1);
        pairs[pos] = s | ((d & 255u) << 17);
    }
}

// ---------------- per-bucket (256 nodes) counting sort -> CSR; 1024 thr, 2 blk/CU ----------

__global__ void __launch_bounds__(1024) k_bsort(const unsigned int* __restrict__ pairs,
                                                const int* __restrict__ bptr,
                                                int* __restrict__ rowptr,
                                                float* __restrict__ dinv,
                                                int* __restrict__ ssrc) {
    __shared__ unsigned int ein[CAP];
    __shared__ unsigned int srt[CAP];
    __shared__ int lcnt[256], lofs[256], lcur[256];
    int b = blockIdx.x;
    int t = threadIdx.x;
    int s0 = bptr[b], s1 = bptr[b + 1];
    int n = s1 - s0;
    for (int i = t; i < n; i += 1024) ein[i] = pairs[s0 + i];
    if (t < 256) lcnt[t] = 0;
    __syncthreads();
    for (int i = t; i < n; i += 1024) atomicAdd(&lcnt[ein[i] >> 17], 1);
    __syncthreads();
    if (t < 256) lofs[t] = lcnt[t];
    __syncthreads();
    for (int off = 1; off < 256; off <<= 1) {
        int add = 0;
        if (t < 256 && t >= off) add = lofs[t - off];
        __syncthreads();
        if (t < 256) lofs[t] += add;
        __syncthreads();
    }
    if (t < 256) {
        int excl = lofs[t] - lcnt[t];
        lcur[t] = excl;
        int node = b * 256 + t;
        if (node < NN) {
            rowptr[node] = s0 + excl;
            dinv[node] = rsqrtf((float)(lcnt[t] + 1));
        }
    }
    __syncthreads();
    for (int i = t; i < n; i += 1024) {
        unsigned int v = ein[i];
        int pos = atomicAdd(&lcur[v >> 17], 1);
        srt[pos] = v & 0x1FFFFu;
    }
    __syncthreads();
    for (int i = t; i < n; i += 1024) ssrc[s0 + i] = (int)srt[i];
}

// ---------------- layer-1 aggregation: one wave per node ----------------
// h1 unscaled: acc = h1[node]*di + sum h1[src]*dinv[src];  r1 = bf16(relu(acc*di+b1)*di)

__global__ void __launch_bounds__(256) k_agg1(const unsigned short* __restrict__ hs,
                                              const int* __restrict__ rowptr,
                                              const int* __restrict__ ssrc,
                                              const float* __restrict__ dinv,
                                              const float* __restrict__ b1,
                                              unsigned short* __restrict__ r1) {
    int l = threadIdx.x & 63;
    int node = blockIdx.x * 4 + (threadIdx.x >> 6);
    int j = l & 15;
    int ec = l >> 4;
    float di = dinv[node];
    int s = rowptr[node];
    int e1 = rowptr[node + 1];
    float acc = (ec == 0) ? b2f(hs[(size_t)node * NH + j]) * di : 0.0f;
#pragma unroll 4
    for (int e = s + ec; e < e1; e += 4) {
        int src = ssrc[e];
        acc += b2f(hs[(size_t)src * NH + j]) * dinv[src];
    }
    acc += __shfl_xor(acc, 16, 64);
    acc += __shfl_xor(acc, 32, 64);
    if (ec == 0) {
        float o = fmaxf(acc * di + b1[j], 0.0f) * di;
        r1[(size_t)node * NH + j] = f2b(o);
    }
}

// ---------------- layer-2 aggregation + classifier + log_softmax ----------------

__global__ void __launch_bounds__(256) k_agg2(const unsigned short* __restrict__ rs,
                                              const int* __restrict__ rowptr,
                                              const int* __restrict__ ssrc,
                                              const float* __restrict__ dinv,
                                              const float* __restrict__ W2,
                                              const float* __restrict__ b2,
                                              float* __restrict__ out) {
    __shared__ float w[NH * NC];
    __shared__ float bb[NC];
    int t = threadIdx.x;
    for (int i = t; i < NH * NC; i += 256) w[i] = W2[i];
    if (t < NC) bb[t] = b2[t];
    __syncthreads();
    int l = t & 63;
    int node = blockIdx.x * 4 + (t >> 6);
    int j = l & 15;
    int ec = l >> 4;
    float di = dinv[node];
    int s = rowptr[node];
    int e1 = rowptr[node + 1];
    float acc = (ec == 0) ? b2f(rs[(size_t)node * NH + j]) : 0.0f;
#pragma unroll 4
    for (int e = s + ec; e < e1; e += 4) {
        int src = ssrc[e];
        acc += b2f(rs[(size_t)src * NH + j]);
    }
    acc += __shfl_xor(acc, 16, 64);
    acc += __shfl_xor(acc, 32, 64);
    float zv = acc * di;
    float lg = (l < NC) ? bb[l] : -1e30f;
#pragma unroll
    for (int k = 0; k < NH; ++k) {
        float zk = __shfl(zv, k, 64);
        if (l < NC) lg += zk * w[k * NC + l];
    }
    float mx = lg;
#pragma unroll
    for (int off = 1; off < 64; off <<= 1) mx = fmaxf(mx, __shfl_xor(mx, off, 64));
    float ex = (l < NC) ? __expf(lg - mx) : 0.0f;
    float sm = ex;
#pragma unroll
    for (int off = 1; off < 64; off <<= 1) sm += __shfl_xor(sm, off, 64);
    if (l < NC) out[(size_t)node * NC + l] = lg - mx - __logf(sm);
}

// ---------------- launch ----------------

extern "C" void kernel_launch(void* const* d_in, const int* in_sizes, int n_in,
                              void* d_out, int out_size, void* d_ws, size_t ws_size,
                              hipStream_t stream) {
    const float* x  = (const float*)d_in[0];
    const int*   ei = (const int*)d_in[1];
    const float* W1 = (const float*)d_in[2];
    const float* b1 = (const float*)d_in[3];
    const float* W2 = (const float*)d_in[4];
    const float* b2 = (const float*)d_in[5];
    float* out = (float*)d_out;

    char* ws = (char*)d_ws;
    size_t off = 0;
    auto alloc = [&](size_t bytes) -> void* {
        void* p = ws + off;
        off += (bytes + 255) & ~(size_t)255;
        return p;
    };
    int* histG      = (int*)alloc((size_t)HISTB * NBKT * 4);     // 2.4 MB
    int* ofsG       = (int*)alloc((size_t)NBKT * SCATB * 4);     // 400 KB
    int* bcnt       = (int*)alloc((size_t)NBKT * 4);
    int* bptr       = (int*)alloc((size_t)(NBKT + 1) * 4);
    int* rowptr     = (int*)alloc((size_t)(NN + 1) * 4);
    float* dinv     = (float*)alloc((size_t)NN * 4);
    unsigned int* pairs = (unsigned int*)alloc((size_t)NE * 4);
    int* ssrc       = (int*)alloc((size_t)NE * 4);
    unsigned short* h1  = (unsigned short*)alloc((size_t)NN * NH * 2);  // bf16, unscaled
    unsigned short* r1  = (unsigned short*)alloc((size_t)NN * NH * 2);  // bf16, pre-scaled

    kA_gemm_hist<<<GEMMB, 256, 0, stream>>>(x, W1, ei, h1, histG);
    k_colscan<<<NBKT, 512, 0, stream>>>(histG, ofsG, bcnt);
    k_bscan<<<1, 512, 0, stream>>>(bcnt, bptr, rowptr);
    k_msscatter<<<SCATB, 1024, 0, stream>>>(ei, bptr, ofsG, pairs);
    k_bsort<<<NBKT, 1024, 0, stream>>>(pairs, bptr, rowptr, dinv, ssrc);
    k_agg1<<<NN / 4, 256, 0, stream>>>(h1, rowptr, ssrc, dinv, b1, r1);
    k_agg2<<<NN / 4, 256, 0, stream>>>(r1, rowptr, ssrc, dinv, W2, b2, out);
}